// Round 1
// baseline (215.637 us; speedup 1.0000x reference)
//
#include <hip/hip_runtime.h>
#include <math.h>

// Problem: B=4096 rows, C=128 logits/labels per row, labels in {0,1}.
// loss = bce + wlsep where
//   bce   = mean over all elems of -log_sigmoid(label ? x : -x)
//   wlsep = (1/Npos) * sum over positives j of log(1 + sum_{i: label_i==0} exp(x_i - x_j))
// (the -1e10 mask terms underflow to exact 0 in fp32 logsumexp; the zero-pad row is the "1")

#define C_DIM 128

__device__ __forceinline__ float neg_log_sigmoid(float z) {
    // -log_sigmoid(z) = max(-z,0) + log1p(exp(-|z|))   (stable)
    return fmaxf(-z, 0.0f) + log1pf(__expf(-fabsf(z)));
}

__global__ __launch_bounds__(256) void bce_wlsep_rows(
        const float* __restrict__ x, const int* __restrict__ t,
        float* __restrict__ partials, int B) {
    const int row  = blockIdx.x * 4 + (threadIdx.x >> 6);
    const int lane = threadIdx.x & 63;
    if (row >= B) return;

    const float2 xv = ((const float2*)(x + (size_t)row * C_DIM))[lane];
    const int2   tv = ((const int2*)(t + (size_t)row * C_DIM))[lane];
    const float x0 = xv.x, x1 = xv.y;
    const int   t0 = tv.x, t1 = tv.y;

    // ---- BCE partial (per-lane, 2 elems) ----
    float bce = neg_log_sigmoid(t0 ? x0 : -x0) + neg_log_sigmoid(t1 ? x1 : -x1);

    // ---- row max over negatives (label==0) ----
    float m = -INFINITY;
    if (t0 == 0) m = x0;
    if (t1 == 0) m = fmaxf(m, x1);
    #pragma unroll
    for (int off = 32; off; off >>= 1) m = fmaxf(m, __shfl_down(m, off, 64));
    m = __shfl(m, 0, 64);

    // ---- T = sum over negatives of exp(x - m) ----
    float T = 0.0f;
    if (t0 == 0) T += __expf(x0 - m);
    if (t1 == 0) T += __expf(x1 - m);
    #pragma unroll
    for (int off = 32; off; off >>= 1) T += __shfl_down(T, off, 64);
    T = __shfl(T, 0, 64);

    // ---- wlsep contributions for positives ----
    float wl = 0.0f, pos = 0.0f;
    if (t0) {
        float a = m - x0;   // m=-inf (no negatives) -> exp(a)=0 -> lse=0, correct
        wl += (a > 0.0f) ? a + __logf(T + __expf(-a)) : log1pf(T * __expf(a));
        pos += 1.0f;
    }
    if (t1) {
        float a = m - x1;
        wl += (a > 0.0f) ? a + __logf(T + __expf(-a)) : log1pf(T * __expf(a));
        pos += 1.0f;
    }

    // ---- wave reduce bce, wl, pos ----
    #pragma unroll
    for (int off = 32; off; off >>= 1) {
        bce += __shfl_down(bce, off, 64);
        wl  += __shfl_down(wl,  off, 64);
        pos += __shfl_down(pos, off, 64);
    }
    if (lane == 0) {
        atomicAdd(&partials[0], bce);
        atomicAdd(&partials[1], wl);
        atomicAdd(&partials[2], pos);
    }
}

__global__ void bce_wlsep_finalize(const float* __restrict__ partials,
                                   float* __restrict__ out, float inv_BC) {
    if (threadIdx.x == 0 && blockIdx.x == 0) {
        float bce = partials[0] * inv_BC;          // -mean(log_sig terms), sign folded in
        float wl  = partials[1] / partials[2];     // sum(lse over positives)/Npos
        out[0] = bce + wl;
    }
}

extern "C" void kernel_launch(void* const* d_in, const int* in_sizes, int n_in,
                              void* d_out, int out_size, void* d_ws, size_t ws_size,
                              hipStream_t stream) {
    const float* x = (const float*)d_in[0];
    const int*   t = (const int*)d_in[1];
    float* out = (float*)d_out;
    float* partials = (float*)d_ws;

    const int total = in_sizes[0];
    const int B = total / C_DIM;

    // d_ws is poisoned with 0xAA before every launch: zero the 3 accumulators.
    hipMemsetAsync(partials, 0, 3 * sizeof(float), stream);

    const int blocks = (B + 3) / 4;  // 4 rows (waves) per 256-thread block
    bce_wlsep_rows<<<blocks, 256, 0, stream>>>(x, t, partials, B);
    bce_wlsep_finalize<<<1, 64, 0, stream>>>(partials, out, 1.0f / (float)total);
}

// Round 2
// 62.774 us; speedup vs baseline: 3.4351x; 3.4351x over previous
//
#include <hip/hip_runtime.h>
#include <math.h>

// B=4096 rows, C=128. labels in {0,1}.
// loss = bce + wlsep:
//   bce   = mean over all elems of -log_sigmoid(label ? x : -x)
//   wlsep = (1/Npos) * sum over positives j of log(1 + sum_{i: label_i==0} exp(x_i - x_j))
// R1 lesson: 3 atomicAdds/wave to one cache line = 164us of XCD line ping-pong.
// R2: block-local reduce -> per-block float4 partial -> single-block final reduce.

#define C_DIM 128

__device__ __forceinline__ float neg_log_sigmoid(float z) {
    // -log_sigmoid(z) = max(-z,0) + log1p(exp(-|z|))   (stable)
    return fmaxf(-z, 0.0f) + log1pf(__expf(-fabsf(z)));
}

__global__ __launch_bounds__(256) void bce_wlsep_rows(
        const float* __restrict__ x, const int* __restrict__ t,
        float4* __restrict__ partials, int B) {
    const int wave = threadIdx.x >> 6;
    const int row  = blockIdx.x * 4 + wave;
    const int lane = threadIdx.x & 63;

    float bce = 0.0f, wl = 0.0f, pos = 0.0f;
    if (row < B) {
        const float2 xv = ((const float2*)(x + (size_t)row * C_DIM))[lane];
        const int2   tv = ((const int2*)(t + (size_t)row * C_DIM))[lane];
        const float x0 = xv.x, x1 = xv.y;
        const int   t0 = tv.x, t1 = tv.y;

        // ---- BCE (2 elems/lane) ----
        bce = neg_log_sigmoid(t0 ? x0 : -x0) + neg_log_sigmoid(t1 ? x1 : -x1);

        // ---- row max over negatives ----
        float m = -INFINITY;
        if (t0 == 0) m = x0;
        if (t1 == 0) m = fmaxf(m, x1);
        #pragma unroll
        for (int off = 32; off; off >>= 1) m = fmaxf(m, __shfl_down(m, off, 64));
        m = __shfl(m, 0, 64);

        // ---- T = sum over negatives of exp(x - m) ----
        float T = 0.0f;
        if (t0 == 0) T += __expf(x0 - m);
        if (t1 == 0) T += __expf(x1 - m);
        #pragma unroll
        for (int off = 32; off; off >>= 1) T += __shfl_down(T, off, 64);
        T = __shfl(T, 0, 64);

        // ---- wlsep for positives ----
        if (t0) {
            float a = m - x0;   // m=-inf (no negatives) -> lse=0, correct
            wl += (a > 0.0f) ? a + __logf(T + __expf(-a)) : log1pf(T * __expf(a));
            pos += 1.0f;
        }
        if (t1) {
            float a = m - x1;
            wl += (a > 0.0f) ? a + __logf(T + __expf(-a)) : log1pf(T * __expf(a));
            pos += 1.0f;
        }
    }

    // ---- wave reduce ----
    #pragma unroll
    for (int off = 32; off; off >>= 1) {
        bce += __shfl_down(bce, off, 64);
        wl  += __shfl_down(wl,  off, 64);
        pos += __shfl_down(pos, off, 64);
    }

    // ---- block reduce (4 waves) via LDS, one float4 store per block ----
    __shared__ float s[3][4];
    if (lane == 0) { s[0][wave] = bce; s[1][wave] = wl; s[2][wave] = pos; }
    __syncthreads();
    if (threadIdx.x == 0) {
        float4 p;
        p.x = s[0][0] + s[0][1] + s[0][2] + s[0][3];
        p.y = s[1][0] + s[1][1] + s[1][2] + s[1][3];
        p.z = s[2][0] + s[2][1] + s[2][2] + s[2][3];
        p.w = 0.0f;
        partials[blockIdx.x] = p;
    }
}

__global__ __launch_bounds__(256) void bce_wlsep_reduce(
        const float4* __restrict__ partials, float* __restrict__ out,
        int nblocks, float inv_BC) {
    const int lane = threadIdx.x & 63;
    const int wave = threadIdx.x >> 6;

    float bce = 0.0f, wl = 0.0f, pos = 0.0f;
    for (int i = threadIdx.x; i < nblocks; i += 256) {
        float4 p = partials[i];
        bce += p.x; wl += p.y; pos += p.z;
    }
    #pragma unroll
    for (int off = 32; off; off >>= 1) {
        bce += __shfl_down(bce, off, 64);
        wl  += __shfl_down(wl,  off, 64);
        pos += __shfl_down(pos, off, 64);
    }
    __shared__ float s[3][4];
    if (lane == 0) { s[0][wave] = bce; s[1][wave] = wl; s[2][wave] = pos; }
    __syncthreads();
    if (threadIdx.x == 0) {
        float b = s[0][0] + s[0][1] + s[0][2] + s[0][3];
        float w = s[1][0] + s[1][1] + s[1][2] + s[1][3];
        float p = s[2][0] + s[2][1] + s[2][2] + s[2][3];
        out[0] = b * inv_BC + w / p;
    }
}

extern "C" void kernel_launch(void* const* d_in, const int* in_sizes, int n_in,
                              void* d_out, int out_size, void* d_ws, size_t ws_size,
                              hipStream_t stream) {
    const float* x = (const float*)d_in[0];
    const int*   t = (const int*)d_in[1];
    float* out = (float*)d_out;
    float4* partials = (float4*)d_ws;

    const int total = in_sizes[0];
    const int B = total / C_DIM;
    const int blocks = (B + 3) / 4;   // 4 rows (waves) per 256-thread block

    bce_wlsep_rows<<<blocks, 256, 0, stream>>>(x, t, partials, B);
    bce_wlsep_reduce<<<1, 256, 0, stream>>>(partials, out, blocks,
                                            1.0f / (float)total);
}